// Round 6
// baseline (366.214 us; speedup 1.0000x reference)
//
#include <hip/hip_runtime.h>
#include <hip/hip_bf16.h>
#include <math.h>

#define BB 2
#define SS 2048
#define HID 2048
#define NH 16
#define NKV 4
#define HD 128
#define NT 32            // K / 64 K-tiles

typedef __bf16 bf16_t;
typedef bf16_t bf16x8 __attribute__((ext_vector_type(8)));
typedef bf16_t bf16x4 __attribute__((ext_vector_type(4)));
typedef float f32x4 __attribute__((ext_vector_type(4)));

#define AS1 __attribute__((address_space(1)))
#define AS3 __attribute__((address_space(3)))

// softmax scale folded into Q at projection time: (1/sqrt(128)) * log2(e)
#define CSC 0.12746231410988061f

__device__ __forceinline__ void gload16(const bf16_t* g, bf16_t* lds) {
    __builtin_amdgcn_global_load_lds((const AS1 void*)g, (AS3 void*)lds, 16, 0, 0);
}

// ---------------------------------------------------------------------------
// Prep kernels
// ---------------------------------------------------------------------------
__global__ __launch_bounds__(256) void rope_tab_kernel(float2* __restrict__ tab)
{
    int i = blockIdx.x * 256 + threadIdx.x;       // s*64 + j
    int j = i & 63, s = i >> 6;
    float freq = expf(-(float)j * 0.14391156831212787f);  // ln(10000)/64
    float sn, cs;
    sincosf((float)s * freq, &sn, &cs);
    tab[i] = make_float2(cs, sn);
}

__global__ __launch_bounds__(256) void cast_hidden_kernel(
    const float* __restrict__ X, bf16_t* __restrict__ Xb)
{
    size_t i = (size_t)(blockIdx.x * 256 + threadIdx.x) * 8;
    float4 a = *reinterpret_cast<const float4*>(X + i);
    float4 b = *reinterpret_cast<const float4*>(X + i + 4);
    bf16x8 v = { (bf16_t)a.x, (bf16_t)a.y, (bf16_t)a.z, (bf16_t)a.w,
                 (bf16_t)b.x, (bf16_t)b.y, (bf16_t)b.z, (bf16_t)b.w };
    *reinterpret_cast<bf16x8*>(Xb + i) = v;
}

// W [K=2048][N] fp32 -> Wt [N][2048] bf16. QKV fused into one [3072][2048].
__global__ __launch_bounds__(256) void transpose_cast_kernel(
    const float* __restrict__ q_w, const float* __restrict__ k_w,
    const float* __restrict__ v_w, const float* __restrict__ o_w,
    bf16_t* __restrict__ Wqkv, bf16_t* __restrict__ Wo)
{
    __shared__ float tile[32][33];
    const float* W; bf16_t* Wt; int N;
    switch (blockIdx.z) {
        case 0: W = q_w; Wt = Wqkv;                       N = 2048; break;
        case 1: W = k_w; Wt = Wqkv + (size_t)2048 * HID;  N = 512;  break;
        case 2: W = v_w; Wt = Wqkv + (size_t)2560 * HID;  N = 512;  break;
        default: W = o_w; Wt = Wo;                        N = 2048; break;
    }
    int n0 = blockIdx.x * 32, k0 = blockIdx.y * 32;
    if (n0 >= N) return;
    int c = threadIdx.x & 31, r0 = threadIdx.x >> 5;
    #pragma unroll
    for (int rr = 0; rr < 32; rr += 8)
        tile[r0 + rr][c] = W[(size_t)(k0 + r0 + rr) * N + n0 + c];
    __syncthreads();
    #pragma unroll
    for (int rr = 0; rr < 32; rr += 8)
        Wt[(size_t)(n0 + r0 + rr) * HID + k0 + c] = (bf16_t)tile[c][r0 + rr];
}

// ---------------------------------------------------------------------------
// 8-phase 256x256 bf16 MFMA GEMM core (T2+T3+T4+T5).
// 512 threads = 8 waves (2M x 4N); wave output 128x64; BK=64; LDS 128 KiB.
// LDS regions: [parity][half] of 128 rows x 64 cols, 16B-slot XOR swizzle
// slot^=(row&7) (inverse-swizzled global source, swizzled ds_read).
// Per tile: 4 phases (mh,kh quadrants), stage 1 half-tile/phase,
// counted s_waitcnt vmcnt(4) once per tile (never 0 in-loop).
// ---------------------------------------------------------------------------
__device__ __forceinline__ void stage_half(
    const bf16_t* __restrict__ g, bf16_t* lds, int w, int l)
{
    #pragma unroll
    for (int i = 0; i < 2; ++i) {
        const int c = w * 64 + l + i * 512;          // 16B chunk 0..1023
        const int r = c >> 3;                        // region row 0..127
        const int s = (c & 7) ^ (r & 7);             // inverse swizzle
        gload16(g + (size_t)r * HID + s * 8, lds + (w * 64 + i * 512) * 8);
    }
}

__device__ __forceinline__ bf16x8 ldsfrag(const bf16_t* reg, int row, int kh, int hi)
{
    const int slot = (kh * 4 + hi) ^ (row & 7);
    return *reinterpret_cast<const bf16x8*>(reg + row * 64 + slot * 8);
}

#define SBAR()   __builtin_amdgcn_s_barrier()
#define SCHED0() __builtin_amdgcn_sched_barrier(0)
#define WAITV4() asm volatile("s_waitcnt vmcnt(4)" ::: "memory")

__device__ __forceinline__ void gemm8_core(
    const bf16_t* __restrict__ A, const bf16_t* __restrict__ Bt,
    int m0, int n0, bf16_t* Abuf, bf16_t* Bbuf, f32x4 (&acc)[8][4])
{
    const int t0 = threadIdx.x;
    const int w = t0 >> 6, lane = t0 & 63, lo = lane & 15, hi = lane >> 4;
    const int wm = w >> 2, wn = w & 3;
    const int brow0 = (wn & 1) * 64;

    const bf16_t* Ag[2] = { A  + (size_t)m0 * HID, A  + (size_t)(m0 + 128) * HID };
    const bf16_t* Bg[2] = { Bt + (size_t)n0 * HID, Bt + (size_t)(n0 + 128) * HID };

    // prologue: tile0 (A0,A1,B0,B1) + tile1 (B0,B1); wait all but newest 4
    stage_half(Ag[0],      Abuf + 0 * 8192, w, lane);
    stage_half(Ag[1],      Abuf + 1 * 8192, w, lane);
    stage_half(Bg[0],      Bbuf + 0 * 8192, w, lane);
    stage_half(Bg[1],      Bbuf + 1 * 8192, w, lane);
    stage_half(Bg[0] + 64, Bbuf + 2 * 8192, w, lane);
    stage_half(Bg[1] + 64, Bbuf + 3 * 8192, w, lane);
    WAITV4();
    SBAR();
    SCHED0();

    for (int t = 0; t < NT; ++t) {
        const int pt = t & 1, pn = pt ^ 1;
        const int tA = (t + 1 < NT) ? t + 1 : NT - 1;   // clamped (keeps vmcnt exact)
        const int tB = (t + 2 < NT) ? t + 2 : NT - 1;
        const bf16_t* ARg = Abuf + (pt * 2 + wm) * 8192;
        const bf16_t* BRg = Bbuf + (pt * 2 + (wn >> 1)) * 8192;
        bf16x8 a[4], b0[4], b1[4];

        // ---- phase 1: read A(mh0,kh0)+B(kh0); stage A0(t+1)
        #pragma unroll
        for (int i = 0; i < 4; ++i) a[i] = ldsfrag(ARg, i * 16 + lo, 0, hi);
        #pragma unroll
        for (int j = 0; j < 4; ++j) b0[j] = ldsfrag(BRg, brow0 + j * 16 + lo, 0, hi);
        stage_half(Ag[0] + tA * 64, Abuf + (pn * 2 + 0) * 8192, w, lane);
        SBAR();
        __builtin_amdgcn_s_setprio(1);
        #pragma unroll
        for (int i = 0; i < 4; ++i)
            #pragma unroll
            for (int j = 0; j < 4; ++j)
                acc[i][j] = __builtin_amdgcn_mfma_f32_16x16x32_bf16(
                    a[i], b0[j], acc[i][j], 0, 0, 0);
        __builtin_amdgcn_s_setprio(0);
        SBAR();
        SCHED0();

        // ---- phase 2: read A(mh0,kh1)+B(kh1); stage A1(t+1)
        #pragma unroll
        for (int i = 0; i < 4; ++i) a[i] = ldsfrag(ARg, i * 16 + lo, 1, hi);
        #pragma unroll
        for (int j = 0; j < 4; ++j) b1[j] = ldsfrag(BRg, brow0 + j * 16 + lo, 1, hi);
        stage_half(Ag[1] + tA * 64, Abuf + (pn * 2 + 1) * 8192, w, lane);
        SBAR();
        __builtin_amdgcn_s_setprio(1);
        #pragma unroll
        for (int i = 0; i < 4; ++i)
            #pragma unroll
            for (int j = 0; j < 4; ++j)
                acc[i][j] = __builtin_amdgcn_mfma_f32_16x16x32_bf16(
                    a[i], b1[j], acc[i][j], 0, 0, 0);
        __builtin_amdgcn_s_setprio(0);
        SBAR();
        SCHED0();

        // ---- phase 3: read A(mh1,kh0); stage B0(t+2); reuse b0
        #pragma unroll
        for (int i = 0; i < 4; ++i) a[i] = ldsfrag(ARg, 64 + i * 16 + lo, 0, hi);
        stage_half(Bg[0] + tB * 64, Bbuf + (pt * 2 + 0) * 8192, w, lane);
        SBAR();
        __builtin_amdgcn_s_setprio(1);
        #pragma unroll
        for (int i = 0; i < 4; ++i)
            #pragma unroll
            for (int j = 0; j < 4; ++j)
                acc[4 + i][j] = __builtin_amdgcn_mfma_f32_16x16x32_bf16(
                    a[i], b0[j], acc[4 + i][j], 0, 0, 0);
        __builtin_amdgcn_s_setprio(0);
        SBAR();
        SCHED0();

        // ---- phase 4: read A(mh1,kh1); stage B1(t+2); vmcnt(4); reuse b1
        #pragma unroll
        for (int i = 0; i < 4; ++i) a[i] = ldsfrag(ARg, 64 + i * 16 + lo, 1, hi);
        stage_half(Bg[1] + tB * 64, Bbuf + (pt * 2 + 1) * 8192, w, lane);
        SBAR();
        __builtin_amdgcn_s_setprio(1);
        #pragma unroll
        for (int i = 0; i < 4; ++i)
            #pragma unroll
            for (int j = 0; j < 4; ++j)
                acc[4 + i][j] = __builtin_amdgcn_mfma_f32_16x16x32_bf16(
                    a[i], b1[j], acc[4 + i][j], 0, 0, 0);
        __builtin_amdgcn_s_setprio(0);
        WAITV4();            // tile t+1 fully landed; tile t+2's B still in flight
        SBAR();
        SCHED0();
    }
}

// ---------------------------------------------------------------------------
// Fused QKV projection (8-phase core) + bias + RoPE + layout shuffle.
// Wqkv [3072][2048]: cols 0-2047 Q, 2048-2559 K, 2560-3071 V.
// grid = 192 blocks (16 m-tiles x 12 n-tiles), XCD-chunked.
// ---------------------------------------------------------------------------
__global__ __launch_bounds__(512, 2) void qkv_gemm8_kernel(
    const bf16_t* __restrict__ X, const bf16_t* __restrict__ Wqkv,
    const float* __restrict__ qb, const float* __restrict__ kb,
    const float* __restrict__ vb, const float2* __restrict__ rope_tab,
    bf16_t* __restrict__ Qo, bf16_t* __restrict__ Ko, bf16_t* __restrict__ Vt)
{
    __shared__ bf16_t Abuf[4 * 8192];    // 64 KB  [parity][half]
    __shared__ bf16_t Bbuf[4 * 8192];    // 64 KB

    const int bid = blockIdx.x;
    const int wg = (bid & 7) * 24 + (bid >> 3);     // bijective XCD swizzle
    const int m0 = (wg / 12) * 256, n0 = (wg % 12) * 256;

    f32x4 acc[8][4];
    #pragma unroll
    for (int m = 0; m < 8; ++m)
        #pragma unroll
        for (int n = 0; n < 4; ++n) acc[m][n] = (f32x4){0.f, 0.f, 0.f, 0.f};

    gemm8_core(X, Wqkv, m0, n0, Abuf, Bbuf, acc);

    const int t0 = threadIdx.x, w = t0 >> 6, lane = t0 & 63;
    const int lo = lane & 15, hi = lane >> 4;
    const int wm = w >> 2, wn = w & 3;
    const int gc0 = n0 + wn * 64;
    const int mode = (gc0 < 2048) ? 0 : (gc0 < 2560 ? 1 : 2);

    #pragma unroll
    for (int j = 0; j < 4; ++j) {
        const int col = gc0 + j * 16 + lo;
        float bv; int hh, d;
        if (mode == 0)      { bv = qb[col];        hh = col >> 7;          d = col & 127; }
        else if (mode == 1) { bv = kb[col - 2048]; hh = (col - 2048) >> 7; d = (col - 2048) & 127; }
        else                { bv = vb[col - 2560]; hh = (col - 2560) >> 7; d = (col - 2560) & 127; }
        const int jj = d >> 1;
        #pragma unroll
        for (int mi = 0; mi < 8; ++mi) {
            const int rowb = m0 + wm * 128 + (mi >> 2) * 64 + (mi & 3) * 16 + hi * 4;
            #pragma unroll
            for (int r = 0; r < 4; ++r) {
                const int rw = rowb + r, b = rw >> 11, s = rw & 2047;
                float v = acc[mi][j][r] + bv;
                if (mode < 2) {
                    float2 cs = rope_tab[s * 64 + jj];
                    float pp = __shfl_xor(v, 1);
                    v = (d & 1) ? (pp * cs.y + v * cs.x)
                                : (v * cs.x - pp * cs.y);
                    if (mode == 0)
                        Qo[((size_t)(b * NH + hh) * SS + s) * HD + d] =
                            (bf16_t)(v * CSC);
                    else
                        Ko[((size_t)(b * NKV + hh) * SS + s) * HD + d] = (bf16_t)v;
                } else {
                    Vt[((size_t)(b * NKV + hh) * HD + d) * SS + s] = (bf16_t)v;
                }
            }
        }
    }
}

// ---------------------------------------------------------------------------
// Output projection (8-phase core): Ab [4096][2048] @ Wo^T -> out fp32.
// grid = 128 blocks (16 m-tiles x 8 n-tiles), XCD-chunked.
// ---------------------------------------------------------------------------
__global__ __launch_bounds__(512, 2) void oproj_gemm8_kernel(
    const bf16_t* __restrict__ Ab, const bf16_t* __restrict__ Wo,
    float* __restrict__ out)
{
    __shared__ bf16_t Abuf[4 * 8192];
    __shared__ bf16_t Bbuf[4 * 8192];

    const int bid = blockIdx.x;
    const int wg = (bid & 7) * 16 + (bid >> 3);     // bijective XCD swizzle
    const int m0 = (wg / 8) * 256, n0 = (wg % 8) * 256;

    f32x4 acc[8][4];
    #pragma unroll
    for (int m = 0; m < 8; ++m)
        #pragma unroll
        for (int n = 0; n < 4; ++n) acc[m][n] = (f32x4){0.f, 0.f, 0.f, 0.f};

    gemm8_core(Ab, Wo, m0, n0, Abuf, Bbuf, acc);

    const int t0 = threadIdx.x, w = t0 >> 6, lane = t0 & 63;
    const int lo = lane & 15, hi = lane >> 4;
    const int wm = w >> 2, wn = w & 3;
    #pragma unroll
    for (int mi = 0; mi < 8; ++mi) {
        const int rowb = m0 + wm * 128 + (mi >> 2) * 64 + (mi & 3) * 16 + hi * 4;
        #pragma unroll
        for (int j = 0; j < 4; ++j) {
            const int col = n0 + wn * 64 + j * 16 + lo;
            #pragma unroll
            for (int r = 0; r < 4; ++r)
                out[(size_t)(rowb + r) * HID + col] = acc[mi][j][r];
        }
    }
}

// ---------------------------------------------------------------------------
// MFMA flash attention v3 (unchanged from R5): single stream/wave,
// block-shared LDS K/V staging, descending-cost block order.
// ---------------------------------------------------------------------------
__global__ __launch_bounds__(256, 4) void attn_kernel(
    const bf16_t* __restrict__ Q, const bf16_t* __restrict__ K,
    const bf16_t* __restrict__ Vt, bf16_t* __restrict__ O)
{
    __shared__ bf16_t Kbuf[2][4096];
    __shared__ bf16_t Vbuf[2][4096];
    __shared__ bf16_t Ps[4][512];

    const int t = threadIdx.x, w = t >> 6, lane = t & 63;
    const int lo = lane & 15, hi = lane >> 4;
    const int bid = blockIdx.x;
    const int b    = (bid >> 2) & 1, hkv = bid & 3;
    const int h    = hkv * 4 + ((bid >> 3) & 3);
    const int ss   = 31 - (bid >> 5);
    const int q0   = ss * 64 + w * 16;
    const int dX   = (q0 + 15) >> 5;
    const int nk   = 2 * ss + 2;

    const bf16_t* Qh = Q  + (size_t)(b * NH  + h)   * SS * HD;
    const bf16_t* Kh = K  + (size_t)(b * NKV + hkv) * SS * HD;
    const bf16_t* Vh = Vt + (size_t)(b * NKV + hkv) * HD * SS;

    int preK[2], preV[2];
    #pragma unroll
    for (int i = 0; i < 2; ++i) {
        const int o = t + i * 256;
        const int krow = o >> 4;
        const int kslot = (o & 15) ^ (krow & 7);
        preK[i] = krow * HD + kslot * 8;
        const int d = o >> 2;
        const int cc = (o & 3) ^ ((d ^ (d >> 2)) & 3);
        preV[i] = d * SS + cc * 8;
    }

    bf16x8 qf[4];
    #pragma unroll
    for (int c = 0; c < 4; ++c)
        qf[c] = *reinterpret_cast<const bf16x8*>(
            Qh + (size_t)(q0 + lo) * HD + c * 32 + hi * 8);

    f32x4 of[8];
    #pragma unroll
    for (int n = 0; n < 8; ++n) of[n] = (f32x4){0.f, 0.f, 0.f, 0.f};
    float m_run = -3.0e38f, l_run = 0.f;

    #pragma unroll
    for (int i = 0; i < 2; ++i) {
        gload16(Kh + preK[i], &Kbuf[0][(w * 64 + i * 256) * 8]);
        gload16(Vh + preV[i], &Vbuf[0][(w * 64 + i * 256) * 8]);
    }

    for (int kt = 0; kt < nk; ++kt) {
        const int cur = kt & 1;
        __syncthreads();
        if (kt + 1 < nk) {
            const int kOff = (kt + 1) * 32 * HD;
            const int vOff = (kt + 1) * 32;
            #pragma unroll
            for (int i = 0; i < 2; ++i) {
                gload16(Kh + kOff + preK[i], &Kbuf[cur ^ 1][(w * 64 + i * 256) * 8]);
                gload16(Vh + vOff + preV[i], &Vbuf[cur ^ 1][(w * 64 + i * 256) * 8]);
            }
        }
        if (kt > dX) continue;

        const bf16_t* Kb = Kbuf[cur];
        f32x4 sfr[2];
        sfr[0] = (f32x4){0.f, 0.f, 0.f, 0.f};
        sfr[1] = (f32x4){0.f, 0.f, 0.f, 0.f};
        #pragma unroll
        for (int kg = 0; kg < 2; ++kg) {
            const int krow = kg * 16 + lo;
            #pragma unroll
            for (int c = 0; c < 4; ++c) {
                const int slot = (c * 4 + hi) ^ (krow & 7);
                bf16x8 kf = *reinterpret_cast<const bf16x8*>(
                    Kb + krow * 128 + slot * 8);
                sfr[kg] = __builtin_amdgcn_mfma_f32_16x16x32_bf16(
                    kf, qf[c], sfr[kg], 0, 0, 0);
            }
        }

        float s[8];
        #pragma unroll
        for (int kg = 0; kg < 2; ++kg)
            #pragma unroll
            for (int r = 0; r < 4; ++r) s[kg * 4 + r] = sfr[kg][r];
        if (kt == dX) {
            const int qrow = q0 + lo;
            #pragma unroll
            for (int kg = 0; kg < 2; ++kg)
                #pragma unroll
                for (int r = 0; r < 4; ++r)
                    if (kt * 32 + kg * 16 + hi * 4 + r > qrow)
                        s[kg * 4 + r] = -3.0e38f;
        }
        float pmax = fmaxf(fmaxf(fmaxf(s[0], s[1]), fmaxf(s[2], s[3])),
                           fmaxf(fmaxf(s[4], s[5]), fmaxf(s[6], s[7])));
        pmax = fmaxf(pmax, __shfl_xor(pmax, 16));
        pmax = fmaxf(pmax, __shfl_xor(pmax, 32));
        if (!__all(pmax - m_run <= 11.5f)) {
            float mnew = fmaxf(m_run, pmax);
            float corr = exp2f(m_run - mnew);
            m_run = mnew;
            l_run *= corr;
            #pragma unroll
            for (int r = 0; r < 4; ++r) {
                float cr = __shfl(corr, hi * 4 + r);
                #pragma unroll
                for (int n = 0; n < 8; ++n) of[n][r] *= cr;
            }
        }
        float e[8], psl = 0.f;
        #pragma unroll
        for (int i = 0; i < 8; ++i) {
            e[i] = exp2f(s[i] - m_run);
            psl += e[i];
        }
        l_run += psl;

        bf16_t* ps = Ps[w];
        #pragma unroll
        for (int kg = 0; kg < 2; ++kg) {
            bf16x4 pk;
            #pragma unroll
            for (int r = 0; r < 4; ++r) pk[r] = (bf16_t)e[kg * 4 + r];
            const int oct = kg * 2 + (hi >> 1);
            *reinterpret_cast<bf16x4*>(ps + (oct * 16 + lo) * 8 + (hi & 1) * 4) = pk;
        }
        bf16x8 pf = *reinterpret_cast<const bf16x8*>(ps + lane * 8);

        const bf16_t* Vb = Vbuf[cur];
        #pragma unroll
        for (int n = 0; n < 8; ++n) {
            const int d = n * 16 + lo;
            const int cc = hi ^ ((d ^ (d >> 2)) & 3);
            bf16x8 vf = *reinterpret_cast<const bf16x8*>(Vb + d * 32 + cc * 8);
            of[n] = __builtin_amdgcn_mfma_f32_16x16x32_bf16(
                pf, vf, of[n], 0, 0, 0);
        }
    }

    float lr = l_run + __shfl_xor(l_run, 16);
    lr += __shfl_xor(lr, 32);
    #pragma unroll
    for (int r = 0; r < 4; ++r) {
        float inv = 1.0f / __shfl(lr, hi * 4 + r);
        bf16_t* dst = O + ((size_t)(b * SS + q0 + hi * 4 + r)) * HID + h * HD;
        #pragma unroll
        for (int n = 0; n < 8; ++n)
            dst[n * 16 + lo] = (bf16_t)(of[n][r] * inv);
    }
}

// ---------------------------------------------------------------------------
extern "C" void kernel_launch(void* const* d_in, const int* in_sizes, int n_in,
                              void* d_out, int out_size, void* d_ws, size_t ws_size,
                              hipStream_t stream)
{
    const float* hidden = (const float*)d_in[0];
    const float* q_w    = (const float*)d_in[1];
    const float* q_b    = (const float*)d_in[2];
    const float* k_w    = (const float*)d_in[3];
    const float* k_b    = (const float*)d_in[4];
    const float* v_w    = (const float*)d_in[5];
    const float* v_b    = (const float*)d_in[6];
    const float* o_w    = (const float*)d_in[7];
    float* out = (float*)d_out;

    bf16_t* p    = (bf16_t*)d_ws;
    bf16_t* Xb   = p; p += (size_t)4096 * 2048;
    bf16_t* Wqkv = p; p += (size_t)3072 * 2048;
    bf16_t* Wo   = p; p += (size_t)2048 * 2048;
    bf16_t* Qb   = p; p += (size_t)BB * NH  * SS * HD;
    bf16_t* Kb   = p; p += (size_t)BB * NKV * SS * HD;
    bf16_t* Vt   = p; p += (size_t)BB * NKV * HD * SS;
    bf16_t* Ab   = p; p += (size_t)4096 * 2048;
    float2* rope_tab = (float2*)p;               // 2048*64 float2 = 1 MiB

    rope_tab_kernel<<<512, 256, 0, stream>>>(rope_tab);
    cast_hidden_kernel<<<4096, 256, 0, stream>>>(hidden, Xb);
    transpose_cast_kernel<<<dim3(64, 64, 4), 256, 0, stream>>>(
        q_w, k_w, v_w, o_w, Wqkv, Wo);
    qkv_gemm8_kernel<<<192, 512, 0, stream>>>(
        Xb, Wqkv, q_b, k_b, v_b, rope_tab, Qb, Kb, Vt);
    attn_kernel<<<1024, 256, 0, stream>>>(Qb, Kb, Vt, Ab);
    oproj_gemm8_kernel<<<128, 512, 0, stream>>>(Ab, Wo, out);
}